// Round 1
// baseline (825.410 us; speedup 1.0000x reference)
//
#include <hip/hip_runtime.h>

// out[b,i,e] = x[b,i] * W[i,e] + bias[i,e]
// B=16384, N_NUM=200, EMB=64. Output fp32, 839 MB -> HBM-write-bound.
//
// Structure: each thread owns ONE float4 column j (W/b register-resident),
// loops over ROWS_PER_BLOCK batch rows with nontemporal float4 stores.
// Grid = (B/ROWS_PER_BLOCK) * JCHUNKS = 256 * 10 = 2560 blocks.

#define N_NUM 200
#define EMB 64
#define ROW_F4 (N_NUM * EMB / 4) /* 3200 float4 per batch row */
#define BLOCK 320                /* 5 waves; 3200/320 = 10 j-chunks */
#define JCHUNKS (ROW_F4 / BLOCK) /* 10 */
#define RPB 64                   /* batch rows per block */

typedef float __attribute__((ext_vector_type(4))) fx4;

__global__ __launch_bounds__(BLOCK) void numproj_kernel(
    const float* __restrict__ x,
    const fx4* __restrict__ W4,
    const fx4* __restrict__ b4,
    fx4* __restrict__ out4,
    int batch) {
    const int jc = (int)blockIdx.x % JCHUNKS;  // j-chunk 0..9
    const int rg = (int)blockIdx.x / JCHUNKS;  // row group
    const int j = jc * BLOCK + (int)threadIdx.x; // fixed float4 index, 0..3199
    const int i = j >> 4;                        // feature index (16 f4/feature)

    // W/b fragment: loaded ONCE, register-resident for all 64 rows.
    const fx4 w = W4[j];
    const fx4 bb = b4[j];

    const int row0 = rg * RPB;
    const float* xp = x + (size_t)row0 * N_NUM + i;
    fx4* op = out4 + (size_t)row0 * ROW_F4 + j;

    if (row0 + RPB <= batch) {
#pragma unroll 4
        for (int r = 0; r < RPB; ++r) {
            const float xv = xp[(size_t)r * N_NUM]; // broadcast across 16 lanes
            fx4 o;
            o.x = fmaf(xv, w.x, bb.x);
            o.y = fmaf(xv, w.y, bb.y);
            o.z = fmaf(xv, w.z, bb.z);
            o.w = fmaf(xv, w.w, bb.w);
            // Streaming output is never re-read: bypass cache pollution.
            __builtin_nontemporal_store(o, op + (size_t)r * ROW_F4);
        }
    } else {
        const int rows = batch - row0;
        for (int r = 0; r < rows; ++r) {
            const float xv = xp[(size_t)r * N_NUM];
            fx4 o;
            o.x = fmaf(xv, w.x, bb.x);
            o.y = fmaf(xv, w.y, bb.y);
            o.z = fmaf(xv, w.z, bb.z);
            o.w = fmaf(xv, w.w, bb.w);
            __builtin_nontemporal_store(o, op + (size_t)r * ROW_F4);
        }
    }
}

extern "C" void kernel_launch(void* const* d_in, const int* in_sizes, int n_in,
                              void* d_out, int out_size, void* d_ws, size_t ws_size,
                              hipStream_t stream) {
    const float* x = (const float*)d_in[0];
    const fx4* W4 = (const fx4*)d_in[1];
    const fx4* b4 = (const fx4*)d_in[2];
    fx4* out4 = (fx4*)d_out;

    const int batch = in_sizes[0] / N_NUM; // 16384
    const int row_groups = (batch + RPB - 1) / RPB;
    numproj_kernel<<<row_groups * JCHUNKS, BLOCK, 0, stream>>>(x, W4, b4, out4, batch);
}